// Round 4
// baseline (4619.567 us; speedup 1.0000x reference)
//
#include <hip/hip_runtime.h>
#include <hip/hip_bf16.h>
#include <stdint.h>

// Problem dims
#define BB 64
#define SS 512
#define EE 256
#define HH 512
#define NWG 32   // scan participants; each owns 16 hidden cols (x5 gates = 80 W cols)

typedef short s16x8 __attribute__((ext_vector_type(8)));
typedef float vf4 __attribute__((ext_vector_type(4)));

// Workspace byte offsets (all 256B aligned). Total = 205,817,856 B (~196.3 MiB)
#define OFF_WBT   0UL           // W bf16 transposed [2560][768]
#define OFF_EMB   3932160UL     // embedding bf16 [100][256]
#define OFF_WIT   3983360UL     // Wi bf16 transposed+padded [112][512]
#define OFF_DTT   4098048UL     // time_deltas transposed f32 [512][64]
#define OFF_FLAGS 4229120UL     // int flags, 65536 dwords (per (t,w,v) lines, both modes)
#define OFF_HBUF  4491264UL     // h bf16 [512][64][512]
#define OFF_ZXP   38045696UL    // zx bf16, MFMA-frag-permuted [512][32][4][5][64][4]

// Control block (assembly/election) lives in the first 64 dwords of out_i:
// [0]=hub xcd (-1), [1]=rank counter, [2]=published, [3]=mode (0=unset,1=SLOW,2=FAST),
// [4..35]=xcd table. Zeroed by init_kernel, fully overwritten later by inten_kernel.

// Flag dword index: line (64B) per (t-block, w, v); t packed 16-per-line.
// Pollers of one line = lane w of wave v in each of 32 WGs -> 32 pollers/line,
// but each poller polls a DIFFERENT line per instruction (lane L -> line L).
__device__ __forceinline__ int fidx(int t, int w, int v) {
  return (((t >> 4) * 128) + w * 4 + v) * 16 + (t & 15);
}

__device__ __forceinline__ unsigned short f2bf(float f) {
  unsigned u = __float_as_uint(f);
  u += 0x7fffu + ((u >> 16) & 1u);   // round-to-nearest-even
  return (unsigned short)(u >> 16);
}
__device__ __forceinline__ float bf2f(unsigned short h) {
  return __uint_as_float(((unsigned)h) << 16);
}
__device__ __forceinline__ float sigmoidf_(float x) { return 1.f / (1.f + __expf(-x)); }
__device__ __forceinline__ float softplusf_(float x) {
  return fmaxf(x, 0.f) + log1pf(__expf(-fabsf(x)));
}
__device__ __forceinline__ float tanhf_(float x) {   // overflow-safe
  float e = __expf(2.f * x);
  return 1.f - 2.f / (e + 1.f);
}

// HW atomic RMW via inline asm: guaranteed global_atomic_add executing at the L2.
// (R2 lesson: __hip_atomic_fetch_add(p,0) is InstCombine'd into an atomic LOAD,
// which lowers to a plain L1-cached global_load -> stale spin -> hang. R3 proved
// this inline-asm RMW correct and L1-proof on hardware.)
__device__ __forceinline__ int atomic_read_l2(const int* p) {
  int f, zero = 0;
  asm volatile("global_atomic_add %0, %1, %2, off sc0\n\ts_waitcnt vmcnt(0)"
               : "=&v"(f) : "v"(p), "v"(zero) : "memory");
  return f;
}

// ---------------- init: dtype conversions / transposes / flag+ctrl zeroing ----------------
__global__ void init_kernel(const float* __restrict__ W, const float* __restrict__ emb,
                            const float* __restrict__ Wi, const float* __restrict__ td,
                            unsigned short* __restrict__ WbT, unsigned short* __restrict__ embB,
                            unsigned short* __restrict__ WiT, float* __restrict__ dtT,
                            int* __restrict__ flags, int* __restrict__ ctrl) {
  unsigned i = blockIdx.x * 256u + threadIdx.x;
  if (i < 1966080u) {               // WbT[c][k] = bf16(W[k][c])
    unsigned c = i / 768u, k = i % 768u;
    WbT[i] = f2bf(W[(size_t)k * 2560u + c]);
    return;
  }
  i -= 1966080u;
  if (i < 25600u) { embB[i] = f2bf(emb[i]); return; }
  i -= 25600u;
  if (i < 57344u) {                 // WiT[c][k] = bf16(Wi[k][c]), pad c=100..111 with 0
    unsigned c = i / 512u, k = i % 512u;
    WiT[i] = f2bf(c < 100u ? Wi[(size_t)k * 100u + c] : 0.f);
    return;
  }
  i -= 57344u;
  if (i < 32768u) {                 // dtT[t][b] = td[b][t]
    unsigned t = i / 64u, b = i % 64u;
    dtT[i] = td[(size_t)b * 512u + t];
    return;
  }
  i -= 32768u;
  if (i < 65536u) { flags[i] = 0; return; }
  i -= 65536u;
  if (i < 64u) { ctrl[i] = (i == 0u) ? -1 : 0; return; }
}

// ---------------- zx = gather(embedding) @ W_x + b, stored bf16 in frag-permuted layout ----
__global__ __launch_bounds__(256, 2)
void zx_kernel(const int* __restrict__ evt, const unsigned short* __restrict__ embB,
               const unsigned short* __restrict__ WbT, const float* __restrict__ bias,
               unsigned short* __restrict__ zxp) {
  const int t = blockIdx.y;
  const int tid = threadIdx.x;
  const int v = tid >> 6, lane = tid & 63;
  const int m = lane & 15, quad = lane >> 4;
  const int cbase = blockIdx.x * 256 + v * 64;  // wave's 64 output cols (4 frags)

  s16x8 Breg[8][4];
#pragma unroll
  for (int cf = 0; cf < 4; ++cf) {
    const unsigned short* bp = WbT + (size_t)(cbase + cf * 16 + m) * 768 + quad * 8;
#pragma unroll
    for (int ch = 0; ch < 8; ++ch) Breg[ch][cf] = *(const s16x8*)(bp + ch * 32);
  }
  int ev[4];
#pragma unroll
  for (int rt = 0; rt < 4; ++rt) ev[rt] = evt[(size_t)(rt * 16 + m) * 512 + t];

  vf4 acc[4][4];
#pragma unroll
  for (int cf = 0; cf < 4; ++cf) {
    float bbv = bias[cbase + cf * 16 + m];
#pragma unroll
    for (int rt = 0; rt < 4; ++rt) acc[rt][cf] = (vf4){bbv, bbv, bbv, bbv};
  }
#pragma unroll
  for (int ch = 0; ch < 8; ++ch) {
#pragma unroll
    for (int rt = 0; rt < 4; ++rt) {
      s16x8 a = *(const s16x8*)(embB + (size_t)ev[rt] * 256 + ch * 32 + quad * 8);
#pragma unroll
      for (int cf = 0; cf < 4; ++cf)
        acc[rt][cf] = __builtin_amdgcn_mfma_f32_16x16x32_bf16(a, Breg[ch][cf], acc[rt][cf], 0, 0, 0);
    }
  }
#pragma unroll
  for (int cf = 0; cf < 4; ++cf) {
    int col0 = cbase + cf * 16;
    int g = col0 >> 9;              // gate index
    int w = (col0 & 511) >> 4;      // scan participant owning these cols
#pragma unroll
    for (int rt = 0; rt < 4; ++rt) {
      unsigned h0 = f2bf(acc[rt][cf][0]);
      unsigned h1 = f2bf(acc[rt][cf][1]);
      unsigned h2 = f2bf(acc[rt][cf][2]);
      unsigned h3 = f2bf(acc[rt][cf][3]);
      uint2 val;
      val.x = h0 | (h1 << 16);
      val.y = h2 | (h3 << 16);
      ((uint2*)zxp)[((((size_t)t * 32 + w) * 4 + rt) * 5 + g) * 64 + lane] = val;
    }
  }
}

// ---------------- persistent sequential scan ----------------
// Wave v of participant w owns batch rows [16v,16v+16) x hidden cols [16w,16w+16).
// FAST mode (all 32 participants on one XCD; engagement verified R1/R3 via FETCH drop):
//   - h stores: plain (write-through L1 -> hub L2); drain = s_waitcnt(0).
//     Visibility of plain-store->waitcnt->publish->plain-load on one XCD was
//     VERIFIED by R1/R3's passing runs.
//   - publish: lane0 PLAIN store of 1 to its own (t,w,v) flag line. 32 parallel
//     lines — no same-address RMW serialization (R3 lesson: one aggregated
//     counter serializes 32 increments + 32 pollers on one dword, ~+1 µs/step).
//   - poll: lanes 0..31 RMW-poll (add 0, sc0) their own producer's line — one
//     vector atomic checks 32 producers in parallel at local-L2 latency,
//     L1-proof by construction (R3-verified primitive). Satisfied lanes drop
//     out of the divergent loop. Insurance: after 2^17 spins fall back to
//     agent-scope loads (R1-proven correct), so a hang is impossible.
//   - h loads: plain; per-t addresses never L1-resident -> refill from hub L2.
// SLOW mode (mixed XCDs): exactly the previously-verified sc1/agent protocol.
template<int FAST>
__device__ __forceinline__
void scan_loop(const int w, const int v, const int lane,
               const unsigned short* __restrict__ WbT,
               const unsigned short* __restrict__ zxp,
               const float* __restrict__ dtT,
               unsigned short* __restrict__ hbuf,
               int* __restrict__ flags,
               float* __restrict__ out_h, float* __restrict__ out_d) {
  const int m = lane & 15, quad = lane >> 4;
  const int rowb = v * 16;
  const int bb0 = rowb + quad * 4;    // first batch row of this lane's C-frag elems
  const int col = w * 16 + m;         // hidden col of this lane's C-frag elems

  // W_h slice resident in registers: Breg[ch][g], k = 256 + ch*32 + quad*8 + j
  s16x8 Breg[16][5];
#pragma unroll
  for (int g = 0; g < 5; ++g) {
    const unsigned short* bp = WbT + (size_t)(g * 512 + w * 16 + m) * 768 + 256 + quad * 8;
#pragma unroll
    for (int ch = 0; ch < 16; ++ch) Breg[ch][g] = *(const s16x8*)(bp + ch * 32);
  }

  vf4 cst = (vf4){0.f, 0.f, 0.f, 0.f};   // cell state (4 rows x this lane's col)

  for (int t = 0; t < 512; ++t) {
    // acc init from zx (independent of recurrence -> issued before the poll)
    vf4 acc[5];
#pragma unroll
    for (int g = 0; g < 5; ++g) {
      uint2 zv = ((const uint2*)zxp)[((((size_t)t * 32 + w) * 4 + v) * 5 + g) * 64 + lane];
      acc[g][0] = bf2f((unsigned short)(zv.x & 0xffffu));
      acc[g][1] = bf2f((unsigned short)(zv.x >> 16));
      acc[g][2] = bf2f((unsigned short)(zv.y & 0xffffu));
      acc[g][3] = bf2f((unsigned short)(zv.y >> 16));
    }
    vf4 dt4 = *(const vf4*)(dtT + t * 64 + bb0);

    if (t > 0) {
      const int tp = t - 1;
      // lane L < 32 polls producer WG L, wave v — parallel lines, divergent loop.
      if (lane < 32) {
        const int* fp = flags + fidx(tp, lane, v);
        if (FAST) {
          int it = 0, f;
          do {
            f = (it < (1 << 17))
                    ? atomic_read_l2(fp)   // local-L2 RMW, L1-proof (R3-verified)
                    : __hip_atomic_load(fp, __ATOMIC_RELAXED, __HIP_MEMORY_SCOPE_AGENT);
            if (f == 0) { __builtin_amdgcn_s_sleep(1); ++it; }
          } while (f == 0);
        } else {
          while (__hip_atomic_load(fp, __ATOMIC_RELAXED, __HIP_MEMORY_SCOPE_AGENT) == 0) {
            __builtin_amdgcn_s_sleep(1);
          }
        }
      }
      // No HW acquire fence: hbuf[t-1] lines are first-touch in this CU's L1;
      // producer's stores reached the (hub L2 in FAST / device in SLOW)
      // serialization point before its flag publish.
      __asm__ __volatile__("" ::: "memory");
      const unsigned short* hsrc =
          hbuf + (size_t)tp * (BB * HH) + (size_t)(rowb + m) * HH + quad * 8;
#pragma unroll
      for (int ch = 0; ch < 16; ++ch) {
        s16x8 a = *(const s16x8*)(hsrc + ch * 32);
#pragma unroll
        for (int g = 0; g < 5; ++g)
          acc[g] = __builtin_amdgcn_mfma_f32_16x16x32_bf16(a, Breg[ch][g], acc[g], 0, 0, 0);
      }
    }

    // gates + state update; publish h on the critical path, fp32 outputs deferred.
    float hv[4], dv[4];
#pragma unroll
    for (int r = 0; r < 4; ++r) {
      float i_ = sigmoidf_(acc[0][r]);
      float f_ = sigmoidf_(acc[1][r]);
      float o_ = sigmoidf_(acc[2][r]);
      float g_ = tanhf_(acc[3][r]);
      float dec = softplusf_(acc[4][r]);
      float cn = f_ * cst[r] + i_ * g_;
      float ct = cn * __expf(-dec * dt4[r]);
      float h_ = o_ * tanhf_(ct);
      cst[r] = ct;
      hv[r] = h_; dv[r] = dec;
      unsigned short hb = f2bf(h_);
      size_t hi = (size_t)t * (BB * HH) + (size_t)(bb0 + r) * HH + col;
      if (FAST) hbuf[hi] = hb;  // plain store -> hub L2 (R1/R3-verified visible)
      else __hip_atomic_store(hbuf + hi, hb, __ATOMIC_RELAXED, __HIP_MEMORY_SCOPE_AGENT);
    }
    // Drain this wave's h-stores (FAST: L2 ack; SLOW: far ack), then publish.
    __asm__ __volatile__("" ::: "memory");
    __builtin_amdgcn_s_waitcnt(0);
    __asm__ __volatile__("" ::: "memory");
    if (lane == 0) {
      if (FAST)
        *(volatile int*)(flags + fidx(t, w, v)) = 1;   // plain parallel publish
      else
        __hip_atomic_store(flags + fidx(t, w, v), 1, __ATOMIC_RELAXED,
                           __HIP_MEMORY_SCOPE_AGENT);
    }
    // Off-critical-path fp32 outputs (drained by next step's waitcnt, overlapped).
#pragma unroll
    for (int r = 0; r < 4; ++r) {
      size_t oo = ((size_t)(bb0 + r) * SS + t) * HH + col;
      out_h[oo] = hv[r];
      out_d[oo] = dv[r];
    }
  }
}

__global__ __launch_bounds__(256, 1)
void scan_kernel(const unsigned short* __restrict__ WbT,
                 const unsigned short* __restrict__ zxp,
                 const float* __restrict__ dtT,
                 unsigned short* __restrict__ hbuf,
                 int* __restrict__ flags,
                 int* __restrict__ ctrl,
                 float* __restrict__ out_h, float* __restrict__ out_d) {
  __shared__ int sh[2];
  if (threadIdx.x == 0) {
    int xcd;
    asm volatile("s_getreg_b32 %0, hwreg(HW_REG_XCC_ID)" : "=s"(xcd));
    xcd &= 0xf;
    // Elect hub XCD: first arriver wins.
    int expct = -1;
    bool won = __hip_atomic_compare_exchange_strong(
        ctrl + 0, &expct, xcd, __ATOMIC_RELAXED, __ATOMIC_RELAXED,
        __HIP_MEMORY_SCOPE_AGENT);
    int tgt = won ? xcd : expct;
    int rank = -1;
    if (xcd == tgt) {
      int r = __hip_atomic_fetch_add(ctrl + 1, 1, __ATOMIC_RELAXED,
                                     __HIP_MEMORY_SCOPE_AGENT);
      if (r < NWG) rank = r;
    }
    if (rank < 0) {
      // Not on hub (or hub full): wait for assembly, then exit. 3 ms timeout opens
      // role claiming to any XCD so assembly can never deadlock (-> SLOW mode).
      unsigned long long t0 = __builtin_amdgcn_s_memrealtime();
      for (;;) {
        if (__hip_atomic_load(ctrl + 1, __ATOMIC_RELAXED, __HIP_MEMORY_SCOPE_AGENT) >= NWG)
          break;
        if (__builtin_amdgcn_s_memrealtime() - t0 > 300000ull) {  // ~3 ms @ 100 MHz
          int r = __hip_atomic_fetch_add(ctrl + 1, 1, __ATOMIC_RELAXED,
                                         __HIP_MEMORY_SCOPE_AGENT);
          if (r < NWG) rank = r;
          break;
        }
        __builtin_amdgcn_s_sleep(32);
      }
    }
    int mode = 0;
    if (rank >= 0) {
      // Publish my XCD; rank 0 decides FAST (all same XCD) vs SLOW and broadcasts.
      __hip_atomic_store(ctrl + 4 + rank, xcd, __ATOMIC_RELAXED, __HIP_MEMORY_SCOPE_AGENT);
      __hip_atomic_fetch_add(ctrl + 2, 1, __ATOMIC_RELEASE, __HIP_MEMORY_SCOPE_AGENT);
      if (rank == 0) {
        while (__hip_atomic_load(ctrl + 2, __ATOMIC_ACQUIRE, __HIP_MEMORY_SCOPE_AGENT) < NWG)
          __builtin_amdgcn_s_sleep(8);
        int same = 1;
        for (int i2 = 1; i2 < NWG; ++i2)
          same &= (__hip_atomic_load(ctrl + 4 + i2, __ATOMIC_RELAXED,
                                     __HIP_MEMORY_SCOPE_AGENT) == xcd);
        mode = same ? 2 : 1;
        __hip_atomic_store(ctrl + 3, mode, __ATOMIC_RELEASE, __HIP_MEMORY_SCOPE_AGENT);
      } else {
        while ((mode = __hip_atomic_load(ctrl + 3, __ATOMIC_ACQUIRE,
                                         __HIP_MEMORY_SCOPE_AGENT)) == 0)
          __builtin_amdgcn_s_sleep(8);
      }
    }
    sh[0] = rank; sh[1] = mode;
  }
  __syncthreads();
  const int rank = sh[0];
  if (rank < 0) return;               // non-participant
  const int mode = sh[1];
  const int v = (int)(threadIdx.x >> 6), lane = (int)(threadIdx.x & 63);
  if (mode == 2)
    scan_loop<1>(rank, v, lane, WbT, zxp, dtT, hbuf, flags, out_h, out_d);
  else
    scan_loop<0>(rank, v, lane, WbT, zxp, dtT, hbuf, flags, out_h, out_d);
}

// ---------------- base_intensities = softplus(h @ Wi + bi) ----------------
__global__ __launch_bounds__(256, 2)
void inten_kernel(const unsigned short* __restrict__ hbuf,
                  const unsigned short* __restrict__ WiT,
                  const float* __restrict__ bi,
                  float* __restrict__ out_i) {
  const int b = blockIdx.y;            // batch row
  const int t0 = blockIdx.x * 64;      // 64 timesteps per WG
  const int tid = threadIdx.x;
  const int v = tid >> 6, lane = tid & 63;
  const int m = lane & 15, quad = lane >> 4;
  const int trow = t0 + v * 16 + m;    // A row = timestep

  vf4 acc[7];
#pragma unroll
  for (int cf = 0; cf < 7; ++cf) {
    int c = cf * 16 + m;
    float bbv = (c < 100) ? bi[c] : 0.f;
    acc[cf] = (vf4){bbv, bbv, bbv, bbv};
  }
  const unsigned short* ha = hbuf + ((size_t)trow * 64 + b) * 512 + quad * 8;
#pragma unroll 4
  for (int ch = 0; ch < 16; ++ch) {
    s16x8 a = *(const s16x8*)(ha + ch * 32);
#pragma unroll
    for (int cf = 0; cf < 7; ++cf) {
      s16x8 bf = *(const s16x8*)(WiT + (size_t)(cf * 16 + m) * 512 + ch * 32 + quad * 8);
      acc[cf] = __builtin_amdgcn_mfma_f32_16x16x32_bf16(a, bf, acc[cf], 0, 0, 0);
    }
  }
#pragma unroll
  for (int cf = 0; cf < 7; ++cf) {
    int c = cf * 16 + m;
#pragma unroll
    for (int r = 0; r < 4; ++r) {
      int tt = t0 + v * 16 + quad * 4 + r;
      if (c < 100) out_i[((size_t)b * 512 + tt) * 100 + c] = softplusf_(acc[cf][r]);
    }
  }
}

extern "C" void kernel_launch(void* const* d_in, const int* in_sizes, int n_in,
                              void* d_out, int out_size, void* d_ws, size_t ws_size,
                              hipStream_t stream) {
  (void)in_sizes; (void)n_in; (void)out_size; (void)ws_size;
  const int*   evt  = (const int*)d_in[0];
  const float* td   = (const float*)d_in[1];
  const float* emb  = (const float*)d_in[2];
  const float* W    = (const float*)d_in[3];
  const float* bias = (const float*)d_in[4];
  const float* Wi   = (const float*)d_in[5];
  const float* bi   = (const float*)d_in[6];

  char* ws = (char*)d_ws;
  unsigned short* WbT  = (unsigned short*)(ws + OFF_WBT);
  unsigned short* embB = (unsigned short*)(ws + OFF_EMB);
  unsigned short* WiT  = (unsigned short*)(ws + OFF_WIT);
  float*          dtT  = (float*)(ws + OFF_DTT);
  int*            flags= (int*)(ws + OFF_FLAGS);
  unsigned short* hbuf = (unsigned short*)(ws + OFF_HBUF);
  unsigned short* zxp  = (unsigned short*)(ws + OFF_ZXP);

  float* out_h = (float*)d_out;
  float* out_d = out_h + (size_t)BB * SS * HH;
  float* out_i = out_d + (size_t)BB * SS * HH;
  int*   ctrl  = (int*)out_i;   // first 64 dwords, re-inited each launch, overwritten by inten

  init_kernel<<<8390, 256, 0, stream>>>(W, emb, Wi, td, WbT, embB, WiT, dtT, flags, ctrl);
  zx_kernel<<<dim3(10, 512), 256, 0, stream>>>(evt, embB, WbT, bias, zxp);
  scan_kernel<<<256, 256, 0, stream>>>(WbT, zxp, dtT, hbuf, flags, ctrl, out_h, out_d);
  inten_kernel<<<dim3(8, 64), 256, 0, stream>>>(hbuf, WiT, bi, out_i);
}

// Round 5
// 3662.666 us; speedup vs baseline: 1.2613x; 1.2613x over previous
//
#include <hip/hip_runtime.h>
#include <hip/hip_bf16.h>
#include <stdint.h>

// Problem dims
#define BB 64
#define SS 512
#define EE 256
#define HH 512
#define NWG 32   // scan workgroups; each owns 16 hidden cols (x5 gates = 80 W cols)

typedef short s16x8 __attribute__((ext_vector_type(8)));
typedef float vf4 __attribute__((ext_vector_type(4)));

// Workspace byte offsets (all 256B aligned). Total = 205,817,856 B (~196.3 MiB)
#define OFF_WBT   0UL           // W bf16 transposed [2560][768]
#define OFF_EMB   3932160UL     // embedding bf16 [100][256]
#define OFF_WIT   3983360UL     // Wi bf16 transposed+padded [112][512]
#define OFF_DTT   4098048UL     // time_deltas transposed f32 [512][64]
#define OFF_FLAGS 4229120UL     // int flags, 65536 dwords (per (t,w,v), line-sharded)
#define OFF_HBUF  4491264UL     // h bf16 [512][64][512]
#define OFF_ZXP   38045696UL    // zx bf16, MFMA-frag-permuted [512][32][4][5][64][4]

// flag dword index: line (64B) per (t-block, w, v); t packed 16-per-line.
__device__ __forceinline__ int fidx(int t, int w, int v) {
  return (((t >> 4) * 128) + w * 4 + v) * 16 + (t & 15);
}

__device__ __forceinline__ unsigned short f2bf(float f) {
  unsigned u = __float_as_uint(f);
  u += 0x7fffu + ((u >> 16) & 1u);   // round-to-nearest-even
  return (unsigned short)(u >> 16);
}
__device__ __forceinline__ float bf2f(unsigned short h) {
  return __uint_as_float(((unsigned)h) << 16);
}
__device__ __forceinline__ float sigmoidf_(float x) { return 1.f / (1.f + __expf(-x)); }
__device__ __forceinline__ float softplusf_(float x) {
  return fmaxf(x, 0.f) + log1pf(__expf(-fabsf(x)));
}
__device__ __forceinline__ float tanhf_(float x) {   // overflow-safe
  float e = __expf(2.f * x);
  return 1.f - 2.f / (e + 1.f);
}

// ---------------- init: dtype conversions / transposes / flag zeroing ----------------
__global__ void init_kernel(const float* __restrict__ W, const float* __restrict__ emb,
                            const float* __restrict__ Wi, const float* __restrict__ td,
                            unsigned short* __restrict__ WbT, unsigned short* __restrict__ embB,
                            unsigned short* __restrict__ WiT, float* __restrict__ dtT,
                            int* __restrict__ flags) {
  unsigned i = blockIdx.x * 256u + threadIdx.x;
  if (i < 1966080u) {               // WbT[c][k] = bf16(W[k][c])
    unsigned c = i / 768u, k = i % 768u;
    WbT[i] = f2bf(W[(size_t)k * 2560u + c]);
    return;
  }
  i -= 1966080u;
  if (i < 25600u) { embB[i] = f2bf(emb[i]); return; }
  i -= 25600u;
  if (i < 57344u) {                 // WiT[c][k] = bf16(Wi[k][c]), pad c=100..111 with 0
    unsigned c = i / 512u, k = i % 512u;
    WiT[i] = f2bf(c < 100u ? Wi[(size_t)k * 100u + c] : 0.f);
    return;
  }
  i -= 57344u;
  if (i < 32768u) {                 // dtT[t][b] = td[b][t]
    unsigned t = i / 64u, b = i % 64u;
    dtT[i] = td[(size_t)b * 512u + t];
    return;
  }
  i -= 32768u;
  if (i < 65536u) { flags[i] = 0; return; }
}

// ---------------- zx = gather(embedding) @ W_x + b, stored bf16 in frag-permuted layout ----
__global__ __launch_bounds__(256, 2)
void zx_kernel(const int* __restrict__ evt, const unsigned short* __restrict__ embB,
               const unsigned short* __restrict__ WbT, const float* __restrict__ bias,
               unsigned short* __restrict__ zxp) {
  const int t = blockIdx.y;
  const int tid = threadIdx.x;
  const int v = tid >> 6, lane = tid & 63;
  const int m = lane & 15, quad = lane >> 4;
  const int cbase = blockIdx.x * 256 + v * 64;  // wave's 64 output cols (4 frags)

  s16x8 Breg[8][4];
#pragma unroll
  for (int cf = 0; cf < 4; ++cf) {
    const unsigned short* bp = WbT + (size_t)(cbase + cf * 16 + m) * 768 + quad * 8;
#pragma unroll
    for (int ch = 0; ch < 8; ++ch) Breg[ch][cf] = *(const s16x8*)(bp + ch * 32);
  }
  int ev[4];
#pragma unroll
  for (int rt = 0; rt < 4; ++rt) ev[rt] = evt[(size_t)(rt * 16 + m) * 512 + t];

  vf4 acc[4][4];
#pragma unroll
  for (int cf = 0; cf < 4; ++cf) {
    float bbv = bias[cbase + cf * 16 + m];
#pragma unroll
    for (int rt = 0; rt < 4; ++rt) acc[rt][cf] = (vf4){bbv, bbv, bbv, bbv};
  }
#pragma unroll
  for (int ch = 0; ch < 8; ++ch) {
#pragma unroll
    for (int rt = 0; rt < 4; ++rt) {
      s16x8 a = *(const s16x8*)(embB + (size_t)ev[rt] * 256 + ch * 32 + quad * 8);
#pragma unroll
      for (int cf = 0; cf < 4; ++cf)
        acc[rt][cf] = __builtin_amdgcn_mfma_f32_16x16x32_bf16(a, Breg[ch][cf], acc[rt][cf], 0, 0, 0);
    }
  }
#pragma unroll
  for (int cf = 0; cf < 4; ++cf) {
    int col0 = cbase + cf * 16;
    int g = col0 >> 9;              // gate index
    int w = (col0 & 511) >> 4;      // scan WG owning these cols
#pragma unroll
    for (int rt = 0; rt < 4; ++rt) {
      unsigned h0 = f2bf(acc[rt][cf][0]);
      unsigned h1 = f2bf(acc[rt][cf][1]);
      unsigned h2 = f2bf(acc[rt][cf][2]);
      unsigned h3 = f2bf(acc[rt][cf][3]);
      uint2 val;
      val.x = h0 | (h1 << 16);
      val.y = h2 | (h3 << 16);
      ((uint2*)zxp)[((((size_t)t * 32 + w) * 4 + rt) * 5 + g) * 64 + lane] = val;
    }
  }
}

// ---------------- persistent sequential scan: 32 WGs, wave-to-wave flag sync ----------------
// Wave v of WG w owns batch rows [16v,16v+16) x hidden cols [16w,16w+16).
// Protocol (R0-verified, 3350 µs base): sc1 h-stores -> waitcnt(0) -> agent flag store;
// consumers agent-poll flags, plain-load h (first-touch freshness).
// NEW vs base: per-CHUNK consumption. K-chunk ch (32 k-cols) depends only on
// producers 2ch, 2ch+1. A ballot-accumulated done-mask lets each chunk's wait end as
// soon as ITS two producers have published; the chunk's A-load is issued immediately
// and the previous chunk's 5 MFMAs run beneath it. h-load latency and ~all MFMA work
// thus overlap the wait for straggler producers instead of following it.
__global__ __launch_bounds__(256, 1)
void scan_kernel(const unsigned short* __restrict__ WbT,
                 const unsigned short* __restrict__ zxp,
                 const float* __restrict__ dtT,
                 unsigned short* __restrict__ hbuf,
                 int* __restrict__ flags,
                 float* __restrict__ out_h, float* __restrict__ out_d) {
  const int w = blockIdx.x;           // 0..31, owns hidden cols [w*16, w*16+16)
  const int tid = threadIdx.x;
  const int v = tid >> 6, lane = tid & 63;
  const int m = lane & 15, quad = lane >> 4;
  const int rowb = v * 16;
  const int bb0 = rowb + quad * 4;    // first batch row of this lane's C-frag elems
  const int col = w * 16 + m;         // hidden col of this lane's C-frag elems

  // W_h slice resident in registers: Breg[ch][g], k = 256 + ch*32 + quad*8 + j
  s16x8 Breg[16][5];
#pragma unroll
  for (int g = 0; g < 5; ++g) {
    const unsigned short* bp = WbT + (size_t)(g * 512 + w * 16 + m) * 768 + 256 + quad * 8;
#pragma unroll
    for (int ch = 0; ch < 16; ++ch) Breg[ch][g] = *(const s16x8*)(bp + ch * 32);
  }

  vf4 cst = (vf4){0.f, 0.f, 0.f, 0.f};   // cell state (4 rows x this lane's col)

  for (int t = 0; t < 512; ++t) {
    // acc init from zx (independent of recurrence -> issued before any wait)
    vf4 acc[5];
#pragma unroll
    for (int g = 0; g < 5; ++g) {
      uint2 zv = ((const uint2*)zxp)[((((size_t)t * 32 + w) * 4 + v) * 5 + g) * 64 + lane];
      acc[g][0] = bf2f((unsigned short)(zv.x & 0xffffu));
      acc[g][1] = bf2f((unsigned short)(zv.x >> 16));
      acc[g][2] = bf2f((unsigned short)(zv.y & 0xffffu));
      acc[g][3] = bf2f((unsigned short)(zv.y >> 16));
    }
    vf4 dt4 = *(const vf4*)(dtT + t * 64 + bb0);

    if (t > 0) {
      const int tp = t - 1;
      const unsigned short* hsrc =
          hbuf + (size_t)tp * (BB * HH) + (size_t)(rowb + m) * HH + quad * 8;
      // done bit L = producer WG L (wave v) has published h[tp].
      unsigned long long done = 0;
      s16x8 areg[16];                 // fully-unrolled chunk pipeline -> static indices
#pragma unroll
      for (int ch = 0; ch < 16; ++ch) {
        const unsigned long long need = 3ull << (2 * ch);
        for (;;) {
          if ((done & need) == need) break;
          int f = 0;
          if (lane < 32 && !((done >> lane) & 1ull))
            f = __hip_atomic_load(flags + fidx(tp, lane, v), __ATOMIC_RELAXED,
                                  __HIP_MEMORY_SCOPE_AGENT);
          done |= __ballot(f != 0);
          if ((done & need) == need) break;
          __builtin_amdgcn_s_sleep(1);
        }
        // Compiler barrier: the chunk load must not be hoisted above the flag
        // observation (same ordering argument as the verified base protocol).
        __asm__ __volatile__("" ::: "memory");
        areg[ch] = *(const s16x8*)(hsrc + ch * 32);   // in flight under MFMAs below
        if (ch > 0) {
#pragma unroll
          for (int g = 0; g < 5; ++g)
            acc[g] = __builtin_amdgcn_mfma_f32_16x16x32_bf16(areg[ch - 1], Breg[ch - 1][g],
                                                             acc[g], 0, 0, 0);
        }
      }
#pragma unroll
      for (int g = 0; g < 5; ++g)
        acc[g] = __builtin_amdgcn_mfma_f32_16x16x32_bf16(areg[15], Breg[15][g],
                                                         acc[g], 0, 0, 0);
    }

    // gates + state update; publish h (sc1, coherence point) on the critical path,
    // fp32 outputs deferred until after the flag store.
    float hv[4], dv[4];
#pragma unroll
    for (int r = 0; r < 4; ++r) {
      float i_ = sigmoidf_(acc[0][r]);
      float f_ = sigmoidf_(acc[1][r]);
      float o_ = sigmoidf_(acc[2][r]);
      float g_ = tanhf_(acc[3][r]);
      float dec = softplusf_(acc[4][r]);
      float cn = f_ * cst[r] + i_ * g_;
      float ct = cn * __expf(-dec * dt4[r]);
      float h_ = o_ * tanhf_(ct);
      cst[r] = ct;
      hv[r] = h_; dv[r] = dec;
      __hip_atomic_store(hbuf + (size_t)t * (BB * HH) + (size_t)(bb0 + r) * HH + col,
                         f2bf(h_), __ATOMIC_RELAXED, __HIP_MEMORY_SCOPE_AGENT);
    }
    // Drain this wave's sc1 h-stores, then publish. (Manual waitcnt instead of a
    // RELEASE store to avoid a possible buffer_wbl2 in the atomic-release lowering.)
    __asm__ __volatile__("" ::: "memory");
    __builtin_amdgcn_s_waitcnt(0);
    __asm__ __volatile__("" ::: "memory");
    if (lane == 0) {
      __hip_atomic_store(flags + fidx(t, w, v), 1, __ATOMIC_RELAXED,
                         __HIP_MEMORY_SCOPE_AGENT);
    }
    // Off-critical-path fp32 outputs (drained by next step's waitcnt, overlapped).
#pragma unroll
    for (int r = 0; r < 4; ++r) {
      size_t oo = ((size_t)(bb0 + r) * SS + t) * HH + col;
      out_h[oo] = hv[r];
      out_d[oo] = dv[r];
    }
  }
}

// ---------------- base_intensities = softplus(h @ Wi + bi) ----------------
__global__ __launch_bounds__(256, 2)
void inten_kernel(const unsigned short* __restrict__ hbuf,
                  const unsigned short* __restrict__ WiT,
                  const float* __restrict__ bi,
                  float* __restrict__ out_i) {
  const int b = blockIdx.y;            // batch row
  const int t0 = blockIdx.x * 64;      // 64 timesteps per WG
  const int tid = threadIdx.x;
  const int v = tid >> 6, lane = tid & 63;
  const int m = lane & 15, quad = lane >> 4;
  const int trow = t0 + v * 16 + m;    // A row = timestep

  vf4 acc[7];
#pragma unroll
  for (int cf = 0; cf < 7; ++cf) {
    int c = cf * 16 + m;
    float bbv = (c < 100) ? bi[c] : 0.f;
    acc[cf] = (vf4){bbv, bbv, bbv, bbv};
  }
  const unsigned short* ha = hbuf + ((size_t)trow * 64 + b) * 512 + quad * 8;
#pragma unroll 4
  for (int ch = 0; ch < 16; ++ch) {
    s16x8 a = *(const s16x8*)(ha + ch * 32);
#pragma unroll
    for (int cf = 0; cf < 7; ++cf) {
      s16x8 bf = *(const s16x8*)(WiT + (size_t)(cf * 16 + m) * 512 + ch * 32 + quad * 8);
      acc[cf] = __builtin_amdgcn_mfma_f32_16x16x32_bf16(a, bf, acc[cf], 0, 0, 0);
    }
  }
#pragma unroll
  for (int cf = 0; cf < 7; ++cf) {
    int c = cf * 16 + m;
#pragma unroll
    for (int r = 0; r < 4; ++r) {
      int tt = t0 + v * 16 + quad * 4 + r;
      if (c < 100) out_i[((size_t)b * 512 + tt) * 100 + c] = softplusf_(acc[cf][r]);
    }
  }
}

extern "C" void kernel_launch(void* const* d_in, const int* in_sizes, int n_in,
                              void* d_out, int out_size, void* d_ws, size_t ws_size,
                              hipStream_t stream) {
  (void)in_sizes; (void)n_in; (void)out_size; (void)ws_size;
  const int*   evt  = (const int*)d_in[0];
  const float* td   = (const float*)d_in[1];
  const float* emb  = (const float*)d_in[2];
  const float* W    = (const float*)d_in[3];
  const float* bias = (const float*)d_in[4];
  const float* Wi   = (const float*)d_in[5];
  const float* bi   = (const float*)d_in[6];

  char* ws = (char*)d_ws;
  unsigned short* WbT  = (unsigned short*)(ws + OFF_WBT);
  unsigned short* embB = (unsigned short*)(ws + OFF_EMB);
  unsigned short* WiT  = (unsigned short*)(ws + OFF_WIT);
  float*          dtT  = (float*)(ws + OFF_DTT);
  int*            flags= (int*)(ws + OFF_FLAGS);
  unsigned short* hbuf = (unsigned short*)(ws + OFF_HBUF);
  unsigned short* zxp  = (unsigned short*)(ws + OFF_ZXP);

  float* out_h = (float*)d_out;
  float* out_d = out_h + (size_t)BB * SS * HH;
  float* out_i = out_d + (size_t)BB * SS * HH;

  init_kernel<<<8388, 256, 0, stream>>>(W, emb, Wi, td, WbT, embB, WiT, dtT, flags);
  zx_kernel<<<dim3(10, 512), 256, 0, stream>>>(evt, embB, WbT, bias, zxp);
  scan_kernel<<<NWG, 256, 0, stream>>>(WbT, zxp, dtT, hbuf, flags, out_h, out_d);
  inten_kernel<<<dim3(8, 64), 256, 0, stream>>>(hbuf, WiT, bi, out_i);
}